// Round 1
// 347.114 us; speedup vs baseline: 1.2576x; 1.2576x over previous
//
#include <hip/hip_runtime.h>

typedef unsigned int u32;
typedef unsigned short u16;
typedef unsigned long long u64;

typedef float f32x4 __attribute__((ext_vector_type(4)));
typedef short bf16x8 __attribute__((ext_vector_type(8)));

#define B_   16
#define C_   128
#define SEQ_ 16384
#define K_   64
#define TS_  64     // samples per tile
#define NT_  8      // tiles per block
#define CHUNK_ 512  // samples per block

// ---- workspace layout (float offsets) ----
constexpr int OFF_EACC = 0;            // [B][K][C] = 131072 floats (atomic accum)
constexpr int OFF_ASUM = 131072;       // [B][K]    = 1024
constexpr int OFF_SM   = 136192;       // [K]
constexpr int OFF_SMC2 = 136256;       // [K] sm[k]*||cw_k||^2 (fp32-exact)
constexpr int OFF_SCALE= 136320;       // [B][C] = 2048

__device__ __forceinline__ u16 f2bf(float f) {
    u32 b = __float_as_uint(f);
    return (u16)((b + 0x7FFFu + ((b >> 16) & 1u)) >> 16);   // RNE
}
__device__ __forceinline__ float scrub(float v) {
    return fminf(fmaxf(v, -1.0e4f), 1.0e4f);
}

// ---------------- k0: prep tables ----------------
__global__ void k0_prep(const float* __restrict__ cw, const float* __restrict__ sm,
                        float* __restrict__ ws) {
    const int t = threadIdx.x;
    if (t < K_) {
        float s2 = 0.f;
        for (int c = 0; c < C_; ++c) { float f = cw[t * C_ + c]; s2 += f * f; }
        float smv = sm[t];
        ws[OFF_SM + t] = smv;
        ws[OFF_SMC2 + t] = smv * s2;
    }
}

// ---------------- k1: MFMA soft-assign encode + aggregate ----------------
// grid = B * (SEQ/CHUNK) = 16*32 = 512 blocks, 256 threads (4 waves)
// GEMM1: dot[s][k] = x.cw  (M=s tile16/wave, N=k=64, inner c=128), x split hi+lo bf16
// GEMM2: e[k][c] += a^T.x  (M=k=64, N=c=32/wave, inner s), a,x single bf16
__global__ __launch_bounds__(256, 2)
void k1_encode(const float* __restrict__ xg, const float* __restrict__ cwg, float* ws) {
    __shared__ __align__(16) u16 xsc_h[TS_ * C_];   // [s][c] hi, XOR-swizzled (s&15)<<3
    __shared__ __align__(16) u16 xsc_l[TS_ * C_];   // [s][c] lo
    __shared__ __align__(16) u16 xcs[C_ * 72];      // [c][s] stride 72, XOR ((c>>3)&7)<<3
    __shared__ __align__(16) u16 alds[K_ * 72];     // [k][s] stride 72
    __shared__ __align__(16) float x2part[16 * 68]; // partial ||x||^2 sums
    __shared__ float x2s[TS_];

    const int t    = threadIdx.x;
    const int lane = t & 63;
    const int w    = t >> 6;        // wave 0..3
    const int lk   = lane & 15;
    const int lg   = lane >> 4;
    const int b      = blockIdx.x >> 5;
    const int s_base = (blockIdx.x & 31) * CHUNK_;

    // codeword fragments (GEMM1 B-operand), bf16 RNE, register-resident:
    // cwf[nt][ks] : lane holds cw[k=lk+16nt][c = 8*lg + 32*ks + j], j=0..7
    bf16x8 cwf[4][4];
#pragma unroll
    for (int nt = 0; nt < 4; ++nt)
#pragma unroll
      for (int ks = 0; ks < 4; ++ks) {
        const float* p = cwg + (size_t)(lk + 16*nt) * C_ + 8*lg + 32*ks;
        float4 v0 = *(const float4*)p;
        float4 v1 = *(const float4*)(p + 4);
        bf16x8 f;
        f[0]=(short)f2bf(v0.x); f[1]=(short)f2bf(v0.y); f[2]=(short)f2bf(v0.z); f[3]=(short)f2bf(v0.w);
        f[4]=(short)f2bf(v1.x); f[5]=(short)f2bf(v1.y); f[6]=(short)f2bf(v1.z); f[7]=(short)f2bf(v1.w);
        cwf[nt][ks] = f;
      }
    float smk[4], smc2k[4];
#pragma unroll
    for (int nt = 0; nt < 4; ++nt) {
        smk[nt]   = ws[OFF_SM   + lk + 16*nt];
        smc2k[nt] = ws[OFF_SMC2 + lk + 16*nt];
    }

    f32x4 acc2[4][2] = {};              // GEMM2 accum, persists across all tiles
    float asacc[4] = {0.f,0.f,0.f,0.f};

    const int sm_ = t & 15;   // staging: c0 = 8*sm_
    const int sg_ = t >> 4;   // staging: s0 = 4*sg_

    // prefetch tile 0 into registers
    float4 vc[8];
    {
        const float* xb = xg + (size_t)(b * C_ + 8*sm_) * SEQ_ + s_base + 4*sg_;
#pragma unroll
        for (int r = 0; r < 8; ++r) vc[r] = *(const float4*)(xb + (size_t)r * SEQ_);
    }

    for (int tile = 0; tile < NT_; ++tile) {
        const int st = s_base + tile * TS_;
        __syncthreads();   // LDS buffers free (prev GEMM2 reads done)

        // ---- stage: split hi/lo, transpose, ||x||^2 partials ----
        {
            u16 H[8][4], L[8][4];
            float x2p[4] = {0.f,0.f,0.f,0.f};
#pragma unroll
            for (int r = 0; r < 8; ++r) {
                float fa[4] = {vc[r].x, vc[r].y, vc[r].z, vc[r].w};
#pragma unroll
                for (int i = 0; i < 4; ++i) {
                    float f = fa[i];
                    u32 bu = __float_as_uint(f);
                    u16 hh = (u16)(bu >> 16);                       // truncate
                    float fh = __uint_as_float((u32)hh << 16);
                    u16 ll = (u16)(__float_as_uint(f - fh) >> 16);  // exact residual, truncated
                    H[r][i] = hh; L[r][i] = ll;
                    x2p[i] = fmaf(f, f, x2p[i]);
                }
            }
            // prefetch next tile (hides HBM latency under GEMM/softmax phases)
            if (tile + 1 < NT_) {
                const float* xb = xg + (size_t)(b * C_ + 8*sm_) * SEQ_ + (st + TS_) + 4*sg_;
#pragma unroll
                for (int r = 0; r < 8; ++r) vc[r] = *(const float4*)(xb + (size_t)r * SEQ_);
            }
            // x_cs [c][s] (hi only), stride 72, XOR-swizzled on the s-offset
#pragma unroll
            for (int r = 0; r < 8; ++r) {
                int c = 8*sm_ + r;
                u64 pk = (u64)H[r][0] | ((u64)H[r][1] << 16) | ((u64)H[r][2] << 32) | ((u64)H[r][3] << 48);
                *(u64*)&xcs[c * 72 + ((4*sg_) ^ ((sm_ & 7) << 3))] = pk;
            }
            // x_sc [s][c] hi+lo, XOR-swizzled columns
#pragma unroll
            for (int i = 0; i < 4; ++i) {
                int s = 4*sg_ + i;
                u32 idx = (u32)(s * C_ + 8*sm_) ^ ((u32)(s & 15) << 3);
                uint4 hw, lw;
                hw.x = (u32)H[0][i] | ((u32)H[1][i] << 16);
                hw.y = (u32)H[2][i] | ((u32)H[3][i] << 16);
                hw.z = (u32)H[4][i] | ((u32)H[5][i] << 16);
                hw.w = (u32)H[6][i] | ((u32)H[7][i] << 16);
                lw.x = (u32)L[0][i] | ((u32)L[1][i] << 16);
                lw.y = (u32)L[2][i] | ((u32)L[3][i] << 16);
                lw.z = (u32)L[4][i] | ((u32)L[5][i] << 16);
                lw.w = (u32)L[6][i] | ((u32)L[7][i] << 16);
                *(uint4*)&xsc_h[idx] = hw;
                *(uint4*)&xsc_l[idx] = lw;
            }
            *(float4*)&x2part[sm_ * 68 + 4*sg_] = make_float4(x2p[0], x2p[1], x2p[2], x2p[3]);
        }
        __syncthreads();

        // ---- ||x||^2 reduction (wave 0) ----
        if (t < TS_) {
            float s2 = 0.f;
#pragma unroll
            for (int p = 0; p < 16; ++p) s2 += x2part[p * 68 + t];
            x2s[t] = s2;
        }

        // ---- GEMM1: dot[s][k], hi+lo MFMA ----
        f32x4 d1[4];
        {
            const int sA = 16*w + lk;   // A-frag row: lane holds x[sA][c]
            bf16x8 ah[4], al[4];
#pragma unroll
            for (int ks = 0; ks < 4; ++ks) {
                u32 idx = (u32)(sA * C_ + 8*lg + 32*ks) ^ ((u32)(sA & 15) << 3);
                ah[ks] = *(const bf16x8*)&xsc_h[idx];
                al[ks] = *(const bf16x8*)&xsc_l[idx];
            }
#pragma unroll
            for (int nt = 0; nt < 4; ++nt) {
                f32x4 a = {0.f, 0.f, 0.f, 0.f};
#pragma unroll
                for (int ks = 0; ks < 4; ++ks) {
                    a = __builtin_amdgcn_mfma_f32_16x16x32_bf16(ah[ks], cwf[nt][ks], a, 0, 0, 0);
                    a = __builtin_amdgcn_mfma_f32_16x16x32_bf16(al[ks], cwf[nt][ks], a, 0, 0, 0);
                }
                d1[nt] = a;
            }
        }
        __syncthreads();   // x2s ready

        // ---- softmax (in-register, samples = 16w + 4*lg + r, k = lk + 16*nt) ----
        {
            float x2r[4], mx[4], pp[4][4], inv[4];
#pragma unroll
            for (int r = 0; r < 4; ++r) { x2r[r] = x2s[16*w + 4*lg + r]; mx[r] = -1.0e30f; }
#pragma unroll
            for (int nt = 0; nt < 4; ++nt)
#pragma unroll
              for (int r = 0; r < 4; ++r) {
                float lv = fmaf(smk[nt], x2r[r] - 2.0f * d1[nt][r], smc2k[nt]);
                lv = scrub(lv);
                pp[nt][r] = lv;
                mx[r] = fmaxf(mx[r], lv);
              }
#pragma unroll
            for (int r = 0; r < 4; ++r) {
                mx[r] = fmaxf(mx[r], __shfl_xor(mx[r], 1));
                mx[r] = fmaxf(mx[r], __shfl_xor(mx[r], 2));
                mx[r] = fmaxf(mx[r], __shfl_xor(mx[r], 4));
                mx[r] = fmaxf(mx[r], __shfl_xor(mx[r], 8));
            }
            float sum[4] = {0.f,0.f,0.f,0.f};
#pragma unroll
            for (int nt = 0; nt < 4; ++nt)
#pragma unroll
              for (int r = 0; r < 4; ++r) {
                float e = __expf(pp[nt][r] - mx[r]);
                pp[nt][r] = e;
                sum[r] += e;
              }
#pragma unroll
            for (int r = 0; r < 4; ++r) {
                sum[r] += __shfl_xor(sum[r], 1);
                sum[r] += __shfl_xor(sum[r], 2);
                sum[r] += __shfl_xor(sum[r], 4);
                sum[r] += __shfl_xor(sum[r], 8);
                inv[r] = 1.0f / sum[r];
            }
#pragma unroll
            for (int nt = 0; nt < 4; ++nt) {
                u16 q[4];
                float sloc = 0.f;
#pragma unroll
                for (int r = 0; r < 4; ++r) {
                    float a = pp[nt][r] * inv[r];
                    sloc += a;
                    q[r] = f2bf(a);
                }
                asacc[nt] += sloc;
                u64 pk = (u64)q[0] | ((u64)q[1] << 16) | ((u64)q[2] << 32) | ((u64)q[3] << 48);
                *(u64*)&alds[(lk + 16*nt) * 72 + 16*w + 4*lg] = pk;
            }
        }
        __syncthreads();   // a_lds ready

        // ---- GEMM2: e[k][c] += a^T . x ----
#pragma unroll
        for (int ss = 0; ss < 2; ++ss) {
            bf16x8 aA[4], bX[2];
#pragma unroll
            for (int mt = 0; mt < 4; ++mt)
                aA[mt] = *(const bf16x8*)&alds[(lk + 16*mt) * 72 + 8*lg + 32*ss];
#pragma unroll
            for (int n = 0; n < 2; ++n) {
                int c = lk + 16*(2*w + n);
                u32 idx = (u32)(c * 72) + (((u32)(8*lg + 32*ss)) ^ (((u32)(c >> 3) & 7) << 3));
                bX[n] = *(const bf16x8*)&xcs[idx];
            }
#pragma unroll
            for (int mt = 0; mt < 4; ++mt)
#pragma unroll
              for (int n = 0; n < 2; ++n)
                acc2[mt][n] = __builtin_amdgcn_mfma_f32_16x16x32_bf16(aA[mt], bX[n], acc2[mt][n], 0, 0, 0);
        }
    }

    // ---- flush: e partials (once per block) ----
    float* eacc = ws + OFF_EACC;
#pragma unroll
    for (int mt = 0; mt < 4; ++mt)
#pragma unroll
      for (int n = 0; n < 2; ++n) {
        const int c = lk + 16*(2*w + n);
#pragma unroll
        for (int r = 0; r < 4; ++r) {
            int k = 16*mt + 4*lg + r;
            atomicAdd(&eacc[(b * K_ + k) * C_ + c], acc2[mt][n][r]);
        }
      }
#pragma unroll
    for (int nt = 0; nt < 4; ++nt) {
        float v = asacc[nt];
        v += __shfl_xor(v, 16);
        v += __shfl_xor(v, 32);
        if (lane < 16) atomicAdd(&ws[OFF_ASUM + b * K_ + lk + 16*nt], v);
    }
}

// ---------------- k2: BN + relu-mean + FC + sigmoid (single block) ----------------
__global__ __launch_bounds__(1024)
void k2_bn_fc(const float* __restrict__ cw,
              const float* __restrict__ bnw, const float* __restrict__ bnb,
              const float* __restrict__ fcw, const float* __restrict__ fcb,
              float* ws) {
    __shared__ float fcw_s[C_][C_ + 1];
    __shared__ float enorm_s[B_ * C_];
    __shared__ float redA[K_][16], redB[K_][16];
    __shared__ float scale_k[K_], bias_k[K_];
    const int t = threadIdx.x;  // 1024
    const float* eacc = ws + OFF_EACC;
    const float* asum = ws + OFF_ASUM;
    for (int i = 0; i < 16; ++i) {
        int idx = i * 1024 + t;
        fcw_s[idx >> 7][idx & 127] = fcw[idx];
    }
    {
        int k = t >> 4, part = t & 15;
        float sv = 0.f, sq2 = 0.f;
        for (int i = 0; i < 128; ++i) {
            int flat = part + (i << 4);
            int bb = flat >> 7, c = flat & 127;
            float e = eacc[(bb * K_ + k) * C_ + c] - asum[bb * K_ + k] * cw[k * C_ + c];
            sv += e; sq2 += e * e;
        }
        redA[k][part] = sv; redB[k][part] = sq2;
    }
    __syncthreads();
    if (t < K_) {
        float sv = 0.f, sq2 = 0.f;
        for (int p = 0; p < 16; ++p) { sv += redA[t][p]; sq2 += redB[t][p]; }
        float mean = sv * (1.f / 2048.f);
        float var  = sq2 * (1.f / 2048.f) - mean * mean;
        float rstd = rsqrtf(fmaxf(var, 0.f) + 1e-5f);
        float g = bnw[t] * rstd;
        scale_k[t] = g;
        bias_k[t]  = bnb[t] - mean * g;
    }
    __syncthreads();
    for (int r = 0; r < 2; ++r) {
        int u = r * 1024 + t;
        int bb = u >> 7, c = u & 127;
        float s = 0.f;
        for (int k = 0; k < K_; ++k) {
            float e = eacc[(bb * K_ + k) * C_ + c] - asum[bb * K_ + k] * cw[k * C_ + c];
            float bnv = e * scale_k[k] + bias_k[k];
            bnv = fminf(fmaxf(bnv, 0.f), 1.0e6f);
            s += bnv;
        }
        enorm_s[u] = s * (1.f / 64.f);
    }
    __syncthreads();
    for (int r = 0; r < 2; ++r) {
        int u = r * 1024 + t;
        int bb = u >> 7, c = u & 127;
        float accv = fcb[c];
        for (int cc = 0; cc < C_; ++cc)
            accv += enorm_s[(bb << 7) + cc] * fcw_s[c][cc];
        ws[OFF_SCALE + u] = 1.f / (1.f + __expf(-accv));
    }
}

// ---------------- k3: out = x * scale[b,c] ----------------
__global__ __launch_bounds__(256)
void k3_scale(const float4* __restrict__ xg, float4* __restrict__ outg,
              const float* __restrict__ ws) {
    const int bc = blockIdx.x;
    const float sc = ws[OFF_SCALE + bc];
    const float4* xr = xg + (size_t)bc * (SEQ_ / 4);
    float4* orow = outg + (size_t)bc * (SEQ_ / 4);
    const int t = threadIdx.x;
    for (int i = 0; i < SEQ_ / 4 / 256; ++i) {
        float4 v = xr[i * 256 + t];
        v.x *= sc; v.y *= sc; v.z *= sc; v.w *= sc;
        orow[i * 256 + t] = v;
    }
}

extern "C" void kernel_launch(void* const* d_in, const int* in_sizes, int n_in,
                              void* d_out, int out_size, void* d_ws, size_t ws_size,
                              hipStream_t stream) {
    const float* x   = (const float*)d_in[0];
    const float* cw  = (const float*)d_in[1];
    const float* sm  = (const float*)d_in[2];
    const float* bnw = (const float*)d_in[3];
    const float* bnb = (const float*)d_in[4];
    const float* fcw = (const float*)d_in[5];
    const float* fcb = (const float*)d_in[6];
    float* ws = (float*)d_ws;

    hipMemsetAsync(ws, 0, (size_t)(OFF_ASUM + B_ * K_) * sizeof(float), stream);
    k0_prep<<<1, 256, 0, stream>>>(cw, sm, ws);
    k1_encode<<<B_ * (SEQ_ / CHUNK_), 256, 0, stream>>>(x, cw, ws);
    k2_bn_fc<<<1, 1024, 0, stream>>>(cw, bnw, bnb, fcw, fcb, ws);
    k3_scale<<<B_ * C_, 256, 0, stream>>>((const float4*)x, (float4*)d_out, ws);
}